// Round 25
// baseline (81.618 us; speedup 1.0000x reference)
//
#include <hip/hip_runtime.h>
#include <math.h>

// HoltWintersDecomposition: x (8192, 2048) f32, sequential per-row recurrence.
// r25 = r24 arithmetic (7-inst rescaled one-rcp step, 57.3us) + TWO producer
// waves for cross-wave TLP:
//   Final model (r13..r24): producer wall = insts/step x ~8cy/inst x 2048.
//   8cy/inst = dependent-VALU latency: a LONE in-order wave hides nothing
//   (r17 ILP-2 = exactly 2x wave-step; r20/r22 latency shaves neutral; only
//   count converts). The untried cure is hardware TLP: two producer waves
//   co-resident on one SIMD round-robin issue -> each fills the other's
//   dependency stalls.
//   Waves 0,4 = producers (16 rows each, lanes 0..15): standard CDNA mapping
//   wid%4 puts both on SIMD0 -> ~2x producer throughput. If mapping differs
//   they run in parallel on separate SIMDs -> exactly neutral. Asymmetric bet.
//   Waves 1,5 = consumers (4 it-groups each); waves 2,3,6,7 spin matching
//   barriers (cheap; avoids exited-wave barrier semantics risk) and take
//   epilogue shares.
// Producer step (r24-validated, absmax 16384): L=(l+EPS)/a, E=D/c1:
//   m=x*L; cL=fma(oma,L,EPS); ie=fma(c2,E,x); u=rcp(E); xlu=m*u;
//   L'=fma(k3,xlu,cL); E'=fma(k2,L',ie).
// Consumers: lte=a*L, D=c1*E, s=D*rcp(lte), y=x*rcp(D) (r17-r24 validated).
// lgkm-only barriers (r22): all cross-wave handoff is through LDS.
// Lessons: r6 parallel-in-time broken; r9 1-tile load lead; r4/r12/r17 no
// multi-chain-per-wave; r23 never feed the chain from LDS.

constexpr int   T    = 2048;
constexpr int   B    = 8192;
constexpr int   RPB  = 32;        // rows per block
constexpr int   TT   = 64;        // steps per tile
constexpr int   NTI  = T / TT;    // 32 tiles
constexpr int   LSX  = 68;        // LDS stride words: 272B rows, 16B-aligned
constexpr float EPS  = 1e-8f;

// barrier draining ONLY LDS counters; global loads/stores stay in flight
__device__ __forceinline__ void lds_barrier() {
    __builtin_amdgcn_sched_barrier(0);
    asm volatile("s_waitcnt lgkmcnt(0)" ::: "memory");
    __builtin_amdgcn_s_barrier();
    __builtin_amdgcn_sched_barrier(0);
}

__global__ __launch_bounds__(512, 1)
void hw_kernel(const float* __restrict__ x,
               const float* __restrict__ pla,
               const float* __restrict__ plg,
               float* __restrict__ out)
{
    __shared__ alignas(16) float LT[2][RPB][LSX];   // L = (l+EPS)/alpha
    __shared__ alignas(16) float ET[2][RPB][LSX];   // E = D/c1

    const int tid  = threadIdx.x;
    const int wid  = tid >> 6;        // 0,4 = producers; 1,5 = consumers
    const int lane = tid & 63;
    const int row0 = blockIdx.x * RPB;

    const float alpha = 1.0f / (1.0f + expf(-pla[0]));
    const float gamma = 1.0f / (1.0f + expf(-plg[0]));
    const float oma = 1.0f - alpha, omg = 1.0f - gamma;
    const float c1  = alpha + gamma - alpha * gamma;
    const float c2  = oma * omg;
    const float inv_a  = 1.0f / alpha;
    const float inv_c1 = 1.0f / c1;
    const float k3  = alpha * inv_c1;
    const float k2  = EPS * gamma * alpha * inv_c1;

    float* __restrict__ lout = out;
    float* __restrict__ sout = out + (size_t)B * T;
    float* __restrict__ yout = out + (size_t)2 * B * T;

    // store-phase lane mapping
    const int cr = lane >> 4;          // 0..3
    const int cc = (lane & 15) << 2;   // 0,4,...,60

    // consumer: reconstruct lte = a*L, D = c1*E; s = D*rcp(lte); y = x*rcp(D)
    auto store_tile = [&](int m, int itlo, int ithi) {
        const int bsel = m & 1;
        const int t0 = m * TT;
        #pragma unroll
        for (int it = itlo; it < ithi; ++it) {
            const int r = 4 * it + cr;
            const size_t g = (size_t)(row0 + r) * T + t0 + cc;
            const float4 vL = *reinterpret_cast<const float4*>(&LT[bsel][r][cc]);
            const float4 vE = *reinterpret_cast<const float4*>(&ET[bsel][r][cc]);
            const float4 xv = *reinterpret_cast<const float4*>(&x[g]);
            float4 vl, vd, vs, vy;
            vl.x = alpha * vL.x;  vl.y = alpha * vL.y;
            vl.z = alpha * vL.z;  vl.w = alpha * vL.w;
            vd.x = c1 * vE.x;     vd.y = c1 * vE.y;
            vd.z = c1 * vE.z;     vd.w = c1 * vE.w;
            vs.x = vd.x * __builtin_amdgcn_rcpf(vl.x);
            vs.y = vd.y * __builtin_amdgcn_rcpf(vl.y);
            vs.z = vd.z * __builtin_amdgcn_rcpf(vl.z);
            vs.w = vd.w * __builtin_amdgcn_rcpf(vl.w);
            vy.x = xv.x * __builtin_amdgcn_rcpf(vd.x);
            vy.y = xv.y * __builtin_amdgcn_rcpf(vd.y);
            vy.z = xv.z * __builtin_amdgcn_rcpf(vd.z);
            vy.w = xv.w * __builtin_amdgcn_rcpf(vd.w);
            *reinterpret_cast<float4*>(&lout[g]) = vl;
            *reinterpret_cast<float4*>(&sout[g]) = vs;
            *reinterpret_cast<float4*>(&yout[g]) = vy;
        }
    };

    if (wid == 0 || wid == 4) {
        // ========== producers: 16 rows each, lanes 0..15 ==========
        const int  pbase = (wid == 4) ? 16 : 0;
        const bool act   = lane < 16;
        const int  prow  = pbase + (lane & 15);       // LDS row 0..31
        const float* __restrict__ xrow =
            x + (size_t)(row0 + (act ? prow : pbase)) * T;

        float L = 0.0f;     // (l + EPS) / alpha
        float E = 1.0f;     // D / c1
        float4 XA[16], XB[16];

        auto loadX = [&](float4* Xb, int k) {
            const float* p = xrow + k * TT;
            #pragma unroll
            for (int i = 0; i < 16; ++i)
                Xb[i] = *reinterpret_cast<const float4*>(p + 4 * i);
        };

        auto do_step = [&](float xt, float& Lo, float& Eo) {
            const float m   = xt * L;                        // || with rcp
            const float cL  = __builtin_fmaf(oma, L, EPS);   // || with rcp
            const float ie  = __builtin_fmaf(c2, E, xt);     // || with rcp
            const float u   = __builtin_amdgcn_rcpf(E);      // chain (one rcp)
            const float xlu = m * u;                         // chain
            const float Ln  = __builtin_fmaf(k3, xlu, cL);   // chain
            const float En  = __builtin_fmaf(k2, Ln, ie);    // chain
            Lo = Ln; Eo = En;
            L = Ln; E = En;
        };

        auto compute_tile = [&](const float4* Xb, int k, bool first) {
            const int bsel = k & 1;
            #pragma unroll
            for (int g = 0; g < 16; ++g) {
                const float4 xv = Xb[g];
                float4 Lv, Ev;
                if (first && g == 0) {
                    // t == 0: lte = x0+EPS, ste = 1+EPS (primed, validated)
                    const float lte0 = xv.x + EPS;
                    L = lte0 * inv_a;
                    E = (lte0 * (1.0f + EPS)) * inv_c1;
                    Lv.x = L; Ev.x = E;
                    do_step(xv.y, Lv.y, Ev.y);
                    do_step(xv.z, Lv.z, Ev.z);
                    do_step(xv.w, Lv.w, Ev.w);
                } else {
                    do_step(xv.x, Lv.x, Ev.x);
                    do_step(xv.y, Lv.y, Ev.y);
                    do_step(xv.z, Lv.z, Ev.z);
                    do_step(xv.w, Lv.w, Ev.w);
                }
                *reinterpret_cast<float4*>(&LT[bsel][prow][4 * g]) = Lv;
                *reinterpret_cast<float4*>(&ET[bsel][prow][4 * g]) = Ev;
            }
        };

        if (act) { loadX(XA, 0); loadX(XB, 1); }
        if (act) compute_tile(XA, 0, true);     // one-time vmcnt wait on XA
        lds_barrier();

        #pragma unroll 1
        for (int k = 1; k < NTI - 1; k += 2) {
            if (act) { loadX(XA, k + 1); compute_tile(XB, k, false); }
            lds_barrier();
            if (act) { loadX(XB, k + 2); compute_tile(XA, k + 1, false); }
            lds_barrier();
        }
        if (act) compute_tile(XB, NTI - 1, false);
        lds_barrier();
    } else if (wid == 1 || wid == 5) {
        // ========== consumers: stores + reconstruction, 4 it-groups each ===
        const int lo = (wid == 1) ? 0 : 4;
        #pragma unroll 1
        for (int k = 0; k < NTI; ++k) {
            if (k > 0) store_tile(k - 1, lo, lo + 4);
            lds_barrier();
        }
    } else {
        // ========== idle waves: match the barrier count (32) ==============
        #pragma unroll 1
        for (int k = 0; k < NTI; ++k) lds_barrier();
    }

    // epilogue: tile 31 (buffer 1), all 8 waves take one it-group each
    store_tile(NTI - 1, wid, wid + 1);
}

extern "C" void kernel_launch(void* const* d_in, const int* in_sizes, int n_in,
                              void* d_out, int out_size, void* d_ws, size_t ws_size,
                              hipStream_t stream) {
    const float* x   = (const float*)d_in[0];
    const float* pla = (const float*)d_in[1];
    const float* plg = (const float*)d_in[2];
    float* out = (float*)d_out;

    dim3 grid(B / RPB);    // 256 blocks -> one per CU
    dim3 block(512);       // waves 0,4 producers; 1,5 consumers; rest barrier-idle
    hw_kernel<<<grid, block, 0, stream>>>(x, pla, plg, out);
}

// Round 26
// 67.518 us; speedup vs baseline: 1.2088x; 1.2088x over previous
//
#include <hip/hip_runtime.h>
#include <math.h>

// HoltWintersDecomposition: x (8192, 2048) f32, sequential per-row recurrence.
// r26 = r24 (best, 57.3us) with the chain rcp replaced by bit-seed + 2 Newton:
//   Model (r13..r25): wall = 2048 x step(67cy); step = issue(~16) + serial
//   cycle (rcp -> xlu -> Ln -> En). Waves/lanes exhausted (r25: co-residency
//   refuted -- it shares the SIMD, it does not shorten a wave's own chain).
//   The unprobed constant is v_rcp_f32 latency (quarter-rate trans op).
//   Range analysis: E = D/c1 with D = l*s + eps*l ~ x + <=0.05 for this data
//   -> E in [0.6, 2.2], positive/normal -> bit-trick seed is safe:
//     u0 = bits(0x7EF127EA - bits(E))   (~5% rel err)
//     2x NR: e = fma(-E,u,1); u = fma(u,e,u)   -> ~1e-4 rel (need only ~1e-2;
//     per-step errors contract at 0.5625/step -> absmax stays O(1e4))
//   NR chain = 5 dependent VALU ~ 20cy replacing rcp_lat. If rcp_lat ~ 40cy
//   -> step ~50cy -> ~45us. If rcp_lat ~ 20cy -> neutral. Discriminating.
//   Consumers keep v_rcp (per-element, non-compounding, slack-rich).
// Structure (r24): 256 blocks x 32 rows; wave0 producer (lanes 0..31, raw-x
// full-tile register prefetch, 1-tile lead); waves 1-2 consumers; lgkm-only
// barriers. Producer step: m=x*L; cL=fma(oma,L,EPS); ie=fma(c2,E,x);
// u=rcp_nr(E); xlu=m*u; L'=fma(k3,xlu,cL); E'=fma(k2,L',ie).
// Lessons: r6 parallel-in-time broken; r9 1-tile load lead; r4/r12/r17/r25
// never split/shrink producer lanes; r23 never feed the chain from LDS.

constexpr int   T    = 2048;
constexpr int   B    = 8192;
constexpr int   RPB  = 32;        // rows per block
constexpr int   TT   = 64;        // steps per tile
constexpr int   NTI  = T / TT;    // 32 tiles
constexpr int   LSX  = 68;        // LDS stride words: 272B rows, 16B-aligned
constexpr float EPS  = 1e-8f;

// barrier draining ONLY LDS counters; global loads/stores stay in flight
__device__ __forceinline__ void lds_barrier() {
    __builtin_amdgcn_sched_barrier(0);
    asm volatile("s_waitcnt lgkmcnt(0)" ::: "memory");
    __builtin_amdgcn_s_barrier();
    __builtin_amdgcn_sched_barrier(0);
}

// fast reciprocal for E in [~0.5, ~3]: bit seed + 2 Newton (~1e-4 rel)
__device__ __forceinline__ float rcp_fast(float d) {
    float u = __int_as_float(0x7EF127EA - __float_as_int(d));
    float e = __builtin_fmaf(-d, u, 1.0f);
    u = __builtin_fmaf(u, e, u);
    e = __builtin_fmaf(-d, u, 1.0f);
    return __builtin_fmaf(u, e, u);
}

__global__ __launch_bounds__(192, 1)
void hw_kernel(const float* __restrict__ x,
               const float* __restrict__ pla,
               const float* __restrict__ plg,
               float* __restrict__ out)
{
    __shared__ alignas(16) float LT[2][RPB][LSX];   // L = (l+EPS)/alpha
    __shared__ alignas(16) float ET[2][RPB][LSX];   // E = D/c1

    const int tid  = threadIdx.x;
    const int wid  = tid >> 6;        // 0 = producer, 1..2 = consumers
    const int lane = tid & 63;
    const int row0 = blockIdx.x * RPB;

    const float alpha = 1.0f / (1.0f + expf(-pla[0]));
    const float gamma = 1.0f / (1.0f + expf(-plg[0]));
    const float oma = 1.0f - alpha, omg = 1.0f - gamma;
    const float c1  = alpha + gamma - alpha * gamma;
    const float c2  = oma * omg;
    const float inv_a  = 1.0f / alpha;
    const float inv_c1 = 1.0f / c1;
    const float k3  = alpha * inv_c1;
    const float k2  = EPS * gamma * alpha * inv_c1;

    float* __restrict__ lout = out;
    float* __restrict__ sout = out + (size_t)B * T;
    float* __restrict__ yout = out + (size_t)2 * B * T;

    // store-phase lane mapping
    const int cr = lane >> 4;          // 0..3
    const int cc = (lane & 15) << 2;   // 0,4,...,60

    // consumer: reconstruct lte = a*L, D = c1*E; s = D*rcp(lte); y = x*rcp(D)
    auto store_tile = [&](int m, int itlo, int ithi) {
        const int bsel = m & 1;
        const int t0 = m * TT;
        #pragma unroll
        for (int it = itlo; it < ithi; ++it) {
            const int r = 4 * it + cr;
            const size_t g = (size_t)(row0 + r) * T + t0 + cc;
            const float4 vL = *reinterpret_cast<const float4*>(&LT[bsel][r][cc]);
            const float4 vE = *reinterpret_cast<const float4*>(&ET[bsel][r][cc]);
            const float4 xv = *reinterpret_cast<const float4*>(&x[g]);
            float4 vl, vd, vs, vy;
            vl.x = alpha * vL.x;  vl.y = alpha * vL.y;
            vl.z = alpha * vL.z;  vl.w = alpha * vL.w;
            vd.x = c1 * vE.x;     vd.y = c1 * vE.y;
            vd.z = c1 * vE.z;     vd.w = c1 * vE.w;
            vs.x = vd.x * __builtin_amdgcn_rcpf(vl.x);
            vs.y = vd.y * __builtin_amdgcn_rcpf(vl.y);
            vs.z = vd.z * __builtin_amdgcn_rcpf(vl.z);
            vs.w = vd.w * __builtin_amdgcn_rcpf(vl.w);
            vy.x = xv.x * __builtin_amdgcn_rcpf(vd.x);
            vy.y = xv.y * __builtin_amdgcn_rcpf(vd.y);
            vy.z = xv.z * __builtin_amdgcn_rcpf(vd.z);
            vy.w = xv.w * __builtin_amdgcn_rcpf(vd.w);
            *reinterpret_cast<float4*>(&lout[g]) = vl;
            *reinterpret_cast<float4*>(&sout[g]) = vs;
            *reinterpret_cast<float4*>(&yout[g]) = vy;
        }
    };

    if (wid == 0) {
        // ================= producer: NR-reciprocal chain ====================
        const bool act = lane < RPB;
        const float* __restrict__ xrow = x + (size_t)(row0 + (act ? lane : 0)) * T;

        float L = 0.0f;     // (l + EPS) / alpha
        float E = 1.0f;     // D / c1
        float4 XA[16], XB[16];

        auto loadX = [&](float4* Xb, int k) {
            const float* p = xrow + k * TT;
            #pragma unroll
            for (int i = 0; i < 16; ++i)
                Xb[i] = *reinterpret_cast<const float4*>(p + 4 * i);
        };

        auto do_step = [&](float xt, float& Lo, float& Eo) {
            const float m   = xt * L;                        // || with NR chain
            const float cL  = __builtin_fmaf(oma, L, EPS);   // ||
            const float ie  = __builtin_fmaf(c2, E, xt);     // ||
            const float u   = rcp_fast(E);                   // chain (~20cy)
            const float xlu = m * u;                         // chain
            const float Ln  = __builtin_fmaf(k3, xlu, cL);   // chain
            const float En  = __builtin_fmaf(k2, Ln, ie);    // chain
            Lo = Ln; Eo = En;
            L = Ln; E = En;
        };

        auto compute_tile = [&](const float4* Xb, int k, bool first) {
            const int bsel = k & 1;
            #pragma unroll
            for (int g = 0; g < 16; ++g) {
                const float4 xv = Xb[g];
                float4 Lv, Ev;
                if (first && g == 0) {
                    // t == 0: lte = x0+EPS, ste = 1+EPS (primed, validated)
                    const float lte0 = xv.x + EPS;
                    L = lte0 * inv_a;
                    E = (lte0 * (1.0f + EPS)) * inv_c1;
                    Lv.x = L; Ev.x = E;
                    do_step(xv.y, Lv.y, Ev.y);
                    do_step(xv.z, Lv.z, Ev.z);
                    do_step(xv.w, Lv.w, Ev.w);
                } else {
                    do_step(xv.x, Lv.x, Ev.x);
                    do_step(xv.y, Lv.y, Ev.y);
                    do_step(xv.z, Lv.z, Ev.z);
                    do_step(xv.w, Lv.w, Ev.w);
                }
                *reinterpret_cast<float4*>(&LT[bsel][lane][4 * g]) = Lv;
                *reinterpret_cast<float4*>(&ET[bsel][lane][4 * g]) = Ev;
            }
        };

        if (act) { loadX(XA, 0); loadX(XB, 1); }
        if (act) compute_tile(XA, 0, true);     // one-time vmcnt wait on XA
        lds_barrier();

        #pragma unroll 1
        for (int k = 1; k < NTI - 1; k += 2) {
            if (act) { loadX(XA, k + 1); compute_tile(XB, k, false); }
            lds_barrier();
            if (act) { loadX(XB, k + 2); compute_tile(XA, k + 1, false); }
            lds_barrier();
        }
        if (act) compute_tile(XB, NTI - 1, false);
        lds_barrier();
    } else {
        // ================= consumers: stores + reconstruction =============
        const int lo = (wid - 1) * 4;            // wave1: 0..3, wave2: 4..7
        #pragma unroll 1
        for (int k = 0; k < NTI; ++k) {
            if (k > 0) store_tile(k - 1, lo, lo + 4);
            lds_barrier();
        }
    }

    // epilogue: tile 31 (buffer 1), all three waves split the 8 store groups
    {
        const int lo = (wid == 0) ? 0 : (wid == 1) ? 2 : 5;
        const int hi = (wid == 0) ? 2 : (wid == 1) ? 5 : 8;
        store_tile(NTI - 1, lo, hi);
    }
}

extern "C" void kernel_launch(void* const* d_in, const int* in_sizes, int n_in,
                              void* d_out, int out_size, void* d_ws, size_t ws_size,
                              hipStream_t stream) {
    const float* x   = (const float*)d_in[0];
    const float* pla = (const float*)d_in[1];
    const float* plg = (const float*)d_in[2];
    float* out = (float*)d_out;

    dim3 grid(B / RPB);    // 256 blocks -> one producer + 2 consumers per CU
    dim3 block(192);       // wave0 producer (32 rows), waves 1-2 consumers
    hw_kernel<<<grid, block, 0, stream>>>(x, pla, plg, out);
}

// Round 27
// 54.672 us; speedup vs baseline: 1.4929x; 1.2350x over previous
//
#include <hip/hip_runtime.h>
#include <math.h>

// HoltWintersDecomposition: x (8192, 2048) f32, sequential per-row recurrence.
// r27 = r24 (best, 57.3us) with the alpha-rescaled product state: removes the
// xlu mul from the serial cycle at equal inst count.
//   State: L = (l+EPS)/alpha, F = D/alpha (D = (l+EPS)(s+EPS)).
//   Then rcp(s+EPS) = (l+EPS)/D = L*u with u = rcp(F), so:
//     m  = x*L; cL = fma(oma,L,EPS); xc = (c1/alpha)*x; ieF = fma(c2,F,xc)
//     u  = rcp(F)                (chain)
//     L' = fma(m, u, cL)         (chain)  <- k3 multiplier gone, xlu gone
//     F' = fma(EPSg, L', ieF)    (chain)
//   7 insts (xc replaces xlu); serial cycle = rcp + 2 fma (was rcp + 3).
//   Consumers: l = a*L, s = F*rcp(L) (alpha cancels), y = x*rcp(a*F).
//   Algebra = r24 modulo constant rescale (validated, absmax 16384).
// Model (r13..r26): wall = 2048 x step; step = rcp_lat(~30) + dep-chain + ~2.7
// cy/inst issue. Rows/waves/ILP are provably neutral (r4/r12/r17/r25); NR
// rcp-replacement regressed (r26); inst floor = 7. This cycle shave is the
// last lever; if neutral, ~57us is the structural floor.
// Structure: 256 blocks x 32 rows; wave0 producer (lanes 0..31, raw-x
// full-tile register prefetch, 1-tile lead); waves 1-2 consumers; lgkm-only
// barriers (r22). Lessons: r6 parallel-in-time broken; r9 1-tile load lead;
// r23 never feed the chain from LDS.

constexpr int   T    = 2048;
constexpr int   B    = 8192;
constexpr int   RPB  = 32;        // rows per block
constexpr int   TT   = 64;        // steps per tile
constexpr int   NTI  = T / TT;    // 32 tiles
constexpr int   LSX  = 68;        // LDS stride words: 272B rows, 16B-aligned
constexpr float EPS  = 1e-8f;

// barrier draining ONLY LDS counters; global loads/stores stay in flight
__device__ __forceinline__ void lds_barrier() {
    __builtin_amdgcn_sched_barrier(0);
    asm volatile("s_waitcnt lgkmcnt(0)" ::: "memory");
    __builtin_amdgcn_s_barrier();
    __builtin_amdgcn_sched_barrier(0);
}

__global__ __launch_bounds__(192, 1)
void hw_kernel(const float* __restrict__ x,
               const float* __restrict__ pla,
               const float* __restrict__ plg,
               float* __restrict__ out)
{
    __shared__ alignas(16) float LT[2][RPB][LSX];   // L = (l+EPS)/alpha
    __shared__ alignas(16) float FT[2][RPB][LSX];   // F = D/alpha

    const int tid  = threadIdx.x;
    const int wid  = tid >> 6;        // 0 = producer, 1..2 = consumers
    const int lane = tid & 63;
    const int row0 = blockIdx.x * RPB;

    const float alpha = 1.0f / (1.0f + expf(-pla[0]));
    const float gamma = 1.0f / (1.0f + expf(-plg[0]));
    const float oma = 1.0f - alpha, omg = 1.0f - gamma;
    const float c1  = alpha + gamma - alpha * gamma;
    const float c2  = oma * omg;
    const float inv_a = 1.0f / alpha;
    const float xsc  = c1 * inv_a;       // xc = xsc * x
    const float kF   = EPS * gamma;      // F' = kF*L' + c2*F + xc

    float* __restrict__ lout = out;
    float* __restrict__ sout = out + (size_t)B * T;
    float* __restrict__ yout = out + (size_t)2 * B * T;

    // store-phase lane mapping
    const int cr = lane >> 4;          // 0..3
    const int cc = (lane & 15) << 2;   // 0,4,...,60

    // consumer: l = a*L; s = F*rcp(L); y = x*rcp(a*F)
    auto store_tile = [&](int m, int itlo, int ithi) {
        const int bsel = m & 1;
        const int t0 = m * TT;
        #pragma unroll
        for (int it = itlo; it < ithi; ++it) {
            const int r = 4 * it + cr;
            const size_t g = (size_t)(row0 + r) * T + t0 + cc;
            const float4 vL = *reinterpret_cast<const float4*>(&LT[bsel][r][cc]);
            const float4 vF = *reinterpret_cast<const float4*>(&FT[bsel][r][cc]);
            const float4 xv = *reinterpret_cast<const float4*>(&x[g]);
            float4 vl, vd, vs, vy;
            vl.x = alpha * vL.x;  vl.y = alpha * vL.y;
            vl.z = alpha * vL.z;  vl.w = alpha * vL.w;
            vd.x = alpha * vF.x;  vd.y = alpha * vF.y;
            vd.z = alpha * vF.z;  vd.w = alpha * vF.w;
            vs.x = vF.x * __builtin_amdgcn_rcpf(vL.x);
            vs.y = vF.y * __builtin_amdgcn_rcpf(vL.y);
            vs.z = vF.z * __builtin_amdgcn_rcpf(vL.z);
            vs.w = vF.w * __builtin_amdgcn_rcpf(vL.w);
            vy.x = xv.x * __builtin_amdgcn_rcpf(vd.x);
            vy.y = xv.y * __builtin_amdgcn_rcpf(vd.y);
            vy.z = xv.z * __builtin_amdgcn_rcpf(vd.z);
            vy.w = xv.w * __builtin_amdgcn_rcpf(vd.w);
            *reinterpret_cast<float4*>(&lout[g]) = vl;
            *reinterpret_cast<float4*>(&sout[g]) = vs;
            *reinterpret_cast<float4*>(&yout[g]) = vy;
        }
    };

    if (wid == 0) {
        // ===== producer: 7 insts/step, cycle = rcp + 2 fma =====
        const bool act = lane < RPB;
        const float* __restrict__ xrow = x + (size_t)(row0 + (act ? lane : 0)) * T;

        float L = 0.0f;     // (l + EPS) / alpha
        float F = 1.0f;     // D / alpha
        float4 XA[16], XB[16];

        auto loadX = [&](float4* Xb, int k) {
            const float* p = xrow + k * TT;
            #pragma unroll
            for (int i = 0; i < 16; ++i)
                Xb[i] = *reinterpret_cast<const float4*>(p + 4 * i);
        };

        auto do_step = [&](float xt, float& Lo, float& Fo) {
            const float u   = __builtin_amdgcn_rcpf(F);      // chain (one rcp)
            const float m   = xt * L;                        // || with rcp
            const float cL  = __builtin_fmaf(oma, L, EPS);   // || with rcp
            const float xc  = xsc * xt;                      // || with rcp
            const float ieF = __builtin_fmaf(c2, F, xc);     // || with rcp
            const float Ln  = __builtin_fmaf(m, u, cL);      // chain
            const float Fn  = __builtin_fmaf(kF, Ln, ieF);   // chain
            Lo = Ln; Fo = Fn;
            L = Ln; F = Fn;
        };

        auto compute_tile = [&](const float4* Xb, int k, bool first) {
            const int bsel = k & 1;
            #pragma unroll
            for (int g = 0; g < 16; ++g) {
                const float4 xv = Xb[g];
                float4 Lv, Fv;
                if (first && g == 0) {
                    // t == 0: lte = x0+EPS, ste = 1+EPS (primed, validated)
                    const float lte0 = xv.x + EPS;
                    L = lte0 * inv_a;
                    F = L * (1.0f + EPS);
                    Lv.x = L; Fv.x = F;
                    do_step(xv.y, Lv.y, Fv.y);
                    do_step(xv.z, Lv.z, Fv.z);
                    do_step(xv.w, Lv.w, Fv.w);
                } else {
                    do_step(xv.x, Lv.x, Fv.x);
                    do_step(xv.y, Lv.y, Fv.y);
                    do_step(xv.z, Lv.z, Fv.z);
                    do_step(xv.w, Lv.w, Fv.w);
                }
                *reinterpret_cast<float4*>(&LT[bsel][lane][4 * g]) = Lv;
                *reinterpret_cast<float4*>(&FT[bsel][lane][4 * g]) = Fv;
            }
        };

        if (act) { loadX(XA, 0); loadX(XB, 1); }
        if (act) compute_tile(XA, 0, true);     // one-time vmcnt wait on XA
        lds_barrier();

        #pragma unroll 1
        for (int k = 1; k < NTI - 1; k += 2) {
            if (act) { loadX(XA, k + 1); compute_tile(XB, k, false); }
            lds_barrier();
            if (act) { loadX(XB, k + 2); compute_tile(XA, k + 1, false); }
            lds_barrier();
        }
        if (act) compute_tile(XB, NTI - 1, false);
        lds_barrier();
    } else {
        // ================= consumers: stores + reconstruction =============
        const int lo = (wid - 1) * 4;            // wave1: 0..3, wave2: 4..7
        #pragma unroll 1
        for (int k = 0; k < NTI; ++k) {
            if (k > 0) store_tile(k - 1, lo, lo + 4);
            lds_barrier();
        }
    }

    // epilogue: tile 31 (buffer 1), all three waves split the 8 store groups
    {
        const int lo = (wid == 0) ? 0 : (wid == 1) ? 2 : 5;
        const int hi = (wid == 0) ? 2 : (wid == 1) ? 5 : 8;
        store_tile(NTI - 1, lo, hi);
    }
}

extern "C" void kernel_launch(void* const* d_in, const int* in_sizes, int n_in,
                              void* d_out, int out_size, void* d_ws, size_t ws_size,
                              hipStream_t stream) {
    const float* x   = (const float*)d_in[0];
    const float* pla = (const float*)d_in[1];
    const float* plg = (const float*)d_in[2];
    float* out = (float*)d_out;

    dim3 grid(B / RPB);    // 256 blocks -> one producer + 2 consumers per CU
    dim3 block(192);       // wave0 producer (32 rows), waves 1-2 consumers
    hw_kernel<<<grid, block, 0, stream>>>(x, pla, plg, out);
}